// Round 7
// baseline (502.894 us; speedup 1.0000x reference)
//
#include <hip/hip_runtime.h>
#include <hip/hip_bf16.h>
#include <cstdint>
#include <cstddef>

// Problem constants (B,S,D,H fixed by the reference)
#define Bc 4
#define Sc 2048
#define Dc 1024
#define Hc 16
// HD = 64

typedef __bf16 bf16;
typedef bf16  bf16x4 __attribute__((ext_vector_type(4)));
typedef bf16  bf16x8 __attribute__((ext_vector_type(8)));
typedef float f32x4  __attribute__((ext_vector_type(4)));

__device__ __forceinline__ void load_lds16(const bf16* g, bf16* l) {
    __builtin_amdgcn_global_load_lds((const __attribute__((address_space(1))) void*)g,
                                     (__attribute__((address_space(3))) void*)l,
                                     16, 0, 0);
}

// 16 fp32 -> two bf16x8
__device__ __forceinline__ void cvt16(const float* __restrict__ g,
                                      bf16x8& lo, bf16x8& hi) {
    const f32x4 a0 = *(const f32x4*)(g);
    const f32x4 a1 = *(const f32x4*)(g + 4);
    const f32x4 a2 = *(const f32x4*)(g + 8);
    const f32x4 a3 = *(const f32x4*)(g + 12);
#pragma unroll
    for (int j = 0; j < 4; j++) {
        lo[j]     = (bf16)a0[j];
        lo[j + 4] = (bf16)a1[j];
        hi[j]     = (bf16)a2[j];
        hi[j + 4] = (bf16)a3[j];
    }
}

__device__ __forceinline__ void store_relu(float* p, float v) { *p = fmaxf(v, 0.0f); }
__device__ __forceinline__ void store_relu(bf16*  p, float v) { *p = (bf16)fmaxf(v, 0.0f); }

// ---------------------------------------------------------------------------
// Weight conversion: 4 weight matrices fp32 -> one concatenated bf16 buffer.
// ---------------------------------------------------------------------------
__global__ __launch_bounds__(256)
void cvt_w4(const float* __restrict__ w0, const float* __restrict__ w1,
            const float* __restrict__ w2, const float* __restrict__ w3,
            bf16* __restrict__ dst, int n16) {
    const int wi = blockIdx.y;
    const float* src = (wi == 0) ? w0 : (wi == 1) ? w1 : (wi == 2) ? w2 : w3;
    bf16* d = dst + (size_t)wi * Dc * Dc;
    const int idx = blockIdx.x * 256 + threadIdx.x;
    if (idx >= n16) return;
    bf16x8 lo, hi;
    cvt16(src + (size_t)idx * 16, lo, hi);
    *(bf16x8*)(d + (size_t)idx * 16)     = lo;
    *(bf16x8*)(d + (size_t)idx * 16 + 8) = hi;
}

#define BM 128
#define BN 128
#define BK 64

// ---------------------------------------------------------------------------
// Fused QKV projection GEMM: grid.z selects (A, W-slice, bias, output).
// A is fp32 (raw inputs q/k/v), converted to bf16 in-register during staging.
// W is pre-converted bf16, staged via global_load_lds. XOR-swizzled LDS.
// z==2 (V projection) writes per-head transposed Vt_g[b][h][hd][s].
// ---------------------------------------------------------------------------
__global__ __launch_bounds__(256)
void qkv_gemm(const float* __restrict__ Aq, const float* __restrict__ Ak,
              const float* __restrict__ Av, const bf16* __restrict__ Wcat,
              const float* __restrict__ b0, const float* __restrict__ b1,
              const float* __restrict__ b2,
              bf16* __restrict__ Qh, bf16* __restrict__ Kh, bf16* __restrict__ VtG,
              int M, int N, int K) {
    __shared__ __align__(16) char pool[36864];
    bf16* lA = (bf16*)pool;                        // [BM*BK] = 16 KB
    bf16* lB = (bf16*)(pool + 16384);              // [BN*BK] = 16 KB

    const int t    = threadIdx.x;
    const int lane = t & 63;
    const int wave = t >> 6;
    const int l15  = lane & 15;
    const int quad = lane >> 4;
    const int z    = blockIdx.z;

    const float* A    = (z == 0) ? Aq : (z == 1) ? Ak : Av;
    const bf16*  W    = Wcat + (size_t)z * Dc * Dc;
    const float* bias = (z == 0) ? b0 : (z == 1) ? b1 : b2;

    const int m0 = blockIdx.x * BM;
    const int n0 = blockIdx.y * BN;
    const int wm = (wave >> 1) * 64;
    const int wn = (wave & 1) * 64;

    f32x4 acc[4][4] = {};

    // A staging (fp32 -> bf16 in reg): thread t covers row t>>1, 32 cols.
    const int fr = t >> 1;                         // 0..127
    const int fh = (t & 1);                        // col half (0/1)
    const float* gA = A + (size_t)(m0 + fr) * K + fh * 32;

    // W staging (global_load_lds, r6 pattern): 4 chunks of 8 elems.
    const int srow = t >> 3;                          // 0..31
    const int cg   = (((t & 7) ^ (srow & 7)) << 3);   // swizzled logical col
    const bf16* gW = W + (size_t)(n0 + srow) * K + cg;
    bf16* lB0 = lB + t * 8;

    for (int k0 = 0; k0 < K; k0 += BK) {
        f32x4 a[8];
#pragma unroll
        for (int g = 0; g < 8; g++) a[g] = *(const f32x4*)(gA + g * 4);
        gA += BK;
        __syncthreads();               // previous tiles fully consumed
#pragma unroll
        for (int c = 0; c < 4; c++)
            load_lds16(gW + (size_t)(32 * c) * K, lB0 + c * 2048);
        gW += BK;
        // A: convert + swizzled ds_write_b128 (pos p = G ^ (row&7))
#pragma unroll
        for (int j = 0; j < 4; j++) {
            bf16x8 pk;
#pragma unroll
            for (int e = 0; e < 4; e++) {
                pk[e]     = (bf16)a[2 * j][e];
                pk[e + 4] = (bf16)a[2 * j + 1][e];
            }
            const int G = fh * 4 + j;
            const int p = G ^ (fr & 7);
            *(bf16x8*)(lA + fr * BK + p * 8) = pk;
        }
        __syncthreads();               // drains vmcnt + lgkm -> published

#pragma unroll
        for (int ks = 0; ks < 2; ks++) {
            const int colp = ((((ks << 2) | quad) ^ (l15 & 7)) << 3);
            bf16x8 af[4], bfr[4];
#pragma unroll
            for (int mt = 0; mt < 4; mt++)
                af[mt] = *(const bf16x8*)(lA + (wm + mt * 16 + l15) * BK + colp);
#pragma unroll
            for (int nt = 0; nt < 4; nt++)
                bfr[nt] = *(const bf16x8*)(lB + (wn + nt * 16 + l15) * BK + colp);
#pragma unroll
            for (int mt = 0; mt < 4; mt++)
#pragma unroll
                for (int nt = 0; nt < 4; nt++)
                    acc[mt][nt] = __builtin_amdgcn_mfma_f32_16x16x32_bf16(
                        af[mt], bfr[nt], acc[mt][nt], 0, 0, 0);
        }
    }

    if (z < 2) {
        bf16* C = (z == 0) ? Qh : Kh;
#pragma unroll
        for (int nt = 0; nt < 4; nt++) {
            const int col = n0 + wn + nt * 16 + l15;
            const float bv = bias[col];
#pragma unroll
            for (int mt = 0; mt < 4; mt++) {
                const int rowb = m0 + wm + mt * 16 + quad * 4;
#pragma unroll
                for (int i = 0; i < 4; i++)
                    C[(size_t)(rowb + i) * N + col] = (bf16)fmaxf(acc[mt][nt][i] + bv, 0.0f);
            }
        }
    } else {
        // Transposed per-head output via LDS transpose (pool reuse).
        __syncthreads();
        bf16* trp = (bf16*)pool;       // tr[w][r][c] = trp[(w*64+r)*72 + c]
#pragma unroll
        for (int nt = 0; nt < 4; nt++) {
            const int col = n0 + wn + nt * 16 + l15;
            const float bv = bias[col];
#pragma unroll
            for (int mt = 0; mt < 4; mt++)
#pragma unroll
                for (int i = 0; i < 4; i++)
                    trp[((wave * 64) + nt * 16 + l15) * 72 + mt * 16 + quad * 4 + i] =
                        (bf16)fmaxf(acc[mt][nt][i] + bv, 0.0f);
        }
        __syncthreads();
        const int r2 = lane >> 3;
        const int c8 = (lane & 7) * 8;
#pragma unroll
        for (int rr = 0; rr < 8; rr++) {
            const int rt = rr * 8 + r2;                  // quadrant col (hd dim)
            const bf16x8 vv = *(const bf16x8*)&trp[((wave * 64) + rt) * 72 + c8];
            const int cg2 = n0 + wn + rt;
            const int h   = cg2 >> 6, hd = cg2 & 63;
            const int mg  = m0 + wm + c8;
            const int b   = mg >> 11, s = mg & (Sc - 1);
            bf16* dst = VtG + ((size_t)(b * Hc + h) * 64 + hd) * Sc + s;
            *(bf16x8*)dst = vv;
        }
    }
}

// ---------------------------------------------------------------------------
// Final output GEMM (r6-proven): C = relu(A bf16 @ W^T bf16 + bias) -> fp32.
// ---------------------------------------------------------------------------
__global__ __launch_bounds__(256)
void gemm_out(const bf16* __restrict__ A, const bf16* __restrict__ W,
              const float* __restrict__ bias, float* __restrict__ C,
              int M, int N, int K) {
    __shared__ __align__(16) char pool[32768];
    bf16* lA = (bf16*)pool;
    bf16* lB = (bf16*)(pool + 16384);

    const int t    = threadIdx.x;
    const int lane = t & 63;
    const int wave = t >> 6;
    const int l15  = lane & 15;
    const int quad = lane >> 4;

    const int m0 = blockIdx.x * BM;
    const int n0 = blockIdx.y * BN;
    const int wm = (wave >> 1) * 64;
    const int wn = (wave & 1) * 64;

    f32x4 acc[4][4] = {};

    const int srow = t >> 3;
    const int cg   = (((t & 7) ^ (srow & 7)) << 3);
    const bf16* gA = A + (size_t)(m0 + srow) * K + cg;
    const bf16* gW = W + (size_t)(n0 + srow) * K + cg;
    bf16* lA0 = lA + t * 8;
    bf16* lB0 = lB + t * 8;

    for (int k0 = 0; k0 < K; k0 += BK) {
        __syncthreads();
#pragma unroll
        for (int c = 0; c < 4; c++) {
            load_lds16(gA + (size_t)(32 * c) * K, lA0 + c * 2048);
            load_lds16(gW + (size_t)(32 * c) * K, lB0 + c * 2048);
        }
        gA += BK; gW += BK;
        __syncthreads();

#pragma unroll
        for (int ks = 0; ks < 2; ks++) {
            const int colp = ((((ks << 2) | quad) ^ (l15 & 7)) << 3);
            bf16x8 af[4], bfr[4];
#pragma unroll
            for (int mt = 0; mt < 4; mt++)
                af[mt] = *(const bf16x8*)(lA + (wm + mt * 16 + l15) * BK + colp);
#pragma unroll
            for (int nt = 0; nt < 4; nt++)
                bfr[nt] = *(const bf16x8*)(lB + (wn + nt * 16 + l15) * BK + colp);
#pragma unroll
            for (int mt = 0; mt < 4; mt++)
#pragma unroll
                for (int nt = 0; nt < 4; nt++)
                    acc[mt][nt] = __builtin_amdgcn_mfma_f32_16x16x32_bf16(
                        af[mt], bfr[nt], acc[mt][nt], 0, 0, 0);
        }
    }

#pragma unroll
    for (int nt = 0; nt < 4; nt++) {
        const int col = n0 + wn + nt * 16 + l15;
        const float bv = bias[col];
#pragma unroll
        for (int mt = 0; mt < 4; mt++) {
            const int rowb = m0 + wm + mt * 16 + quad * 4;
#pragma unroll
            for (int i = 0; i < 4; i++)
                store_relu(&C[(size_t)(rowb + i) * N + col], acc[mt][nt][i] + bv);
        }
    }
}

// ---------------------------------------------------------------------------
// Flash attention, barrier-free main loop. 64 queries/block; wave w owns key
// tiles w, w+4, ... (16 tiles of 32 keys), staged into WAVE-PRIVATE LDS via
// global_load_lds + per-wave vmcnt drain (no __syncthreads in the loop).
// Fixed-max softmax (Q,K post-ReLU => scores >= 0), exp2 domain.
// XOR-swizzled K/V LDS layouts keep all b128 reads ~2-way.
// Cross-wave yacc/lrun reduction at the end (4 barriers total).
// ---------------------------------------------------------------------------
__global__ __launch_bounds__(256)
void attn_flash(const bf16* __restrict__ Qh, const bf16* __restrict__ Kh,
                const bf16* __restrict__ Vt_g, bf16* __restrict__ Y) {
    // pool: Kw[4][32*64] | Vw[4][64*32] | Pw[4][64*36]  = 51200 B
    __shared__ __align__(16) bf16 pool[4 * 2048 + 4 * 2048 + 4 * 2304];
    bf16* Kw = pool;
    bf16* Vw = pool + 8192;
    bf16* Pw = pool + 16384;

    const int t    = threadIdx.x;
    const int lane = t & 63;
    const int wave = t >> 6;
    const int l15  = lane & 15;
    const int quad = lane >> 4;

    const int qt = blockIdx.x;          // 0..31
    const int bh = blockIdx.y;          // 0..63
    const int b  = bh >> 4;
    const int h  = bh & 15;
    const int q0 = qt * 64;
    const size_t rowbase = (size_t)b * Sc;
    const size_t vhead   = (size_t)(b * Hc + h) * 64;

    // Q fragments as B-operand [n=query=l15][k=hd], prescaled into exp2 domain.
    const float qscale = 0.125f * 1.44269504f;
    bf16x8 qf[4][2];
#pragma unroll
    for (int qi = 0; qi < 4; qi++) {
        const bf16* qp = Qh + (rowbase + q0 + qi * 16 + l15) * (size_t)Dc + h * 64;
#pragma unroll
        for (int ks = 0; ks < 2; ks++) {
            const bf16x8 raw = *(const bf16x8*)(qp + ks * 32 + quad * 8);
            bf16x8 sc;
#pragma unroll
            for (int j = 0; j < 8; j++) sc[j] = (bf16)((float)raw[j] * qscale);
            qf[qi][ks] = sc;
        }
    }

    float lrun[4] = {0.f, 0.f, 0.f, 0.f};
    f32x4 yacc[4][4] = {};              // O^T: col=query=l15, row=hd

    bf16* KwW = Kw + wave * 2048;
    bf16* VwW = Vw + wave * 2048;
    bf16* PwW = Pw + wave * 2304;

    // DMA lane maps (constant across tiles/chunks)
    const int kR = lane >> 3;                         // K: row within chunk (0..7)
    const int kG = (lane & 7) ^ (kR & 7);             // K: logical hd group
    const int vR = lane >> 2;                         // V: row within chunk (0..15)
    const int vG = (lane & 3) ^ ((lane >> 3) & 3);    // V: logical key group

    for (int kt = wave; kt < Sc / 32; kt += 4) {
        const int kb = kt * 32;
        // ---- wave-private staging via global_load_lds ----
#pragma unroll
        for (int c = 0; c < 4; c++) {
            const int r = 8 * c + kR;   // local key 0..31
            load_lds16(Kh + (rowbase + kb + r) * (size_t)Dc + h * 64 + kG * 8,
                       KwW + c * 512 + lane * 8);
        }
#pragma unroll
        for (int c = 0; c < 4; c++) {
            const int r = 16 * c + vR;  // hd row 0..63
            load_lds16(Vt_g + (vhead + r) * (size_t)Sc + kb + vG * 8,
                       VwW + c * 512 + lane * 8);
        }
        asm volatile("s_waitcnt vmcnt(0)" ::: "memory");  // own DMA done

        // ---- K fragments: A[m=key=mt*16+l15][k=hd], swizzled ----
        bf16x8 kf[2][2];
#pragma unroll
        for (int mt = 0; mt < 2; mt++)
#pragma unroll
            for (int ks = 0; ks < 2; ks++) {
                const int p = ((ks << 2) | quad) ^ (l15 & 7);
                kf[mt][ks] = *(const bf16x8*)(KwW + (mt * 16 + l15) * 64 + p * 8);
            }
        // ---- V fragments: A[m=hd=nt*16+l15][k=key], swizzled ----
        bf16x8 vf[4];
#pragma unroll
        for (int nt = 0; nt < 4; nt++) {
            const int p = quad ^ ((l15 >> 1) & 3);
            vf[nt] = *(const bf16x8*)(VwW + (nt * 16 + l15) * 32 + p * 8);
        }

#pragma unroll
        for (int qi = 0; qi < 4; qi++) {
            // scores S^T: col=query=l15, row=key=mt*16+quad*4+i
            f32x4 s[2];
#pragma unroll
            for (int mt = 0; mt < 2; mt++) {
                s[mt] = (f32x4){0.f, 0.f, 0.f, 0.f};
                s[mt] = __builtin_amdgcn_mfma_f32_16x16x32_bf16(
                    kf[mt][0], qf[qi][0], s[mt], 0, 0, 0);
                s[mt] = __builtin_amdgcn_mfma_f32_16x16x32_bf16(
                    kf[mt][1], qf[qi][1], s[mt], 0, 0, 0);
            }
            // fixed-max softmax: p = exp2(s); in-lane partial sum
            float sum = 0.f;
#pragma unroll
            for (int mt = 0; mt < 2; mt++) {
                bf16x4 pk;
#pragma unroll
                for (int i = 0; i < 4; i++) {
                    const float p = exp2f(s[mt][i]);
                    sum += p;
                    pk[i] = (bf16)p;
                }
                *(bf16x4*)(PwW + (qi * 16 + l15) * 36 + mt * 16 + quad * 4) = pk;
            }
            lrun[qi] += sum;
            // P^T as B-operand [n=query=l15][k=key=quad*8+j]
            const bf16x8 pf = *(const bf16x8*)(PwW + (qi * 16 + l15) * 36 + quad * 8);
#pragma unroll
            for (int nt = 0; nt < 4; nt++)
                yacc[qi][nt] = __builtin_amdgcn_mfma_f32_16x16x32_bf16(
                    vf[nt], pf, yacc[qi][nt], 0, 0, 0);
        }
    }

    // ---- cross-wave reduction (lane layouts identical across waves) ----
    float* red = (float*)pool;          // 2 regions x 64 lanes x 68 floats
    __syncthreads();                    // main loops done everywhere
    if (wave >= 2) {
        float* my = red + (size_t)((wave - 2) * 64 + lane) * 68;
#pragma unroll
        for (int qi = 0; qi < 4; qi++)
#pragma unroll
            for (int nt = 0; nt < 4; nt++)
                *(f32x4*)(my + (qi * 4 + nt) * 4) = yacc[qi][nt];
        *(f32x4*)(my + 64) = (f32x4){lrun[0], lrun[1], lrun[2], lrun[3]};
    }
    __syncthreads();
    if (wave < 2) {
        const float* src = red + (size_t)(wave * 64 + lane) * 68;
#pragma unroll
        for (int qi = 0; qi < 4; qi++)
#pragma unroll
            for (int nt = 0; nt < 4; nt++)
                yacc[qi][nt] += *(const f32x4*)(src + (qi * 4 + nt) * 4);
        const f32x4 lr = *(const f32x4*)(src + 64);
#pragma unroll
        for (int qi = 0; qi < 4; qi++) lrun[qi] += lr[qi];
    }
    __syncthreads();
    if (wave == 1) {
        float* my = red + (size_t)lane * 68;
#pragma unroll
        for (int qi = 0; qi < 4; qi++)
#pragma unroll
            for (int nt = 0; nt < 4; nt++)
                *(f32x4*)(my + (qi * 4 + nt) * 4) = yacc[qi][nt];
        *(f32x4*)(my + 64) = (f32x4){lrun[0], lrun[1], lrun[2], lrun[3]};
    }
    __syncthreads();
    if (wave == 0) {
        const float* src = red + (size_t)lane * 68;
#pragma unroll
        for (int qi = 0; qi < 4; qi++)
#pragma unroll
            for (int nt = 0; nt < 4; nt++)
                yacc[qi][nt] += *(const f32x4*)(src + (qi * 4 + nt) * 4);
        const f32x4 lr = *(const f32x4*)(src + 64);
#pragma unroll
        for (int qi = 0; qi < 4; qi++) {
            float l = lrun[qi] + lr[qi];
            l += __shfl_xor(l, 16);
            l += __shfl_xor(l, 32);
            const float inv = 1.0f / l;
            bf16* yp = Y + (rowbase + q0 + qi * 16 + l15) * (size_t)Dc + h * 64;
#pragma unroll
            for (int nt = 0; nt < 4; nt++) {
                bf16x4 o;
#pragma unroll
                for (int i = 0; i < 4; i++) o[i] = (bf16)(yacc[qi][nt][i] * inv);
                *(bf16x4*)(yp + nt * 16 + quad * 4) = o;
            }
        }
    }
}

// ---------------------------------------------------------------------------
extern "C" void kernel_launch(void* const* d_in, const int* in_sizes, int n_in,
                              void* d_out, int out_size, void* d_ws, size_t ws_size,
                              hipStream_t stream) {
    const float* q  = (const float*)d_in[0];
    const float* k  = (const float*)d_in[1];
    const float* v  = (const float*)d_in[2];
    const float* Wq = (const float*)d_in[3];
    const float* bq = (const float*)d_in[4];
    const float* Wk = (const float*)d_in[5];
    const float* bk = (const float*)d_in[6];
    const float* Wv = (const float*)d_in[7];
    const float* bv = (const float*)d_in[8];
    const float* Wo = (const float*)d_in[9];
    const float* bo = (const float*)d_in[10];
    float* out = (float*)d_out;

    const int M = Bc * Sc;   // 8192
    const int N = Dc;        // 1024
    const int K = Dc;        // 1024
    const size_t E  = (size_t)Bc * Sc * Dc;  // 8388608
    const size_t EW = (size_t)Dc * Dc;       // 1048576

    // d_out: Qh | Kh (bf16; dead before final GEMM writes fp32).
    // d_ws:  Wcat (4 weights bf16) | VtG | Yw  = 41.9 MB (proven footprint).
    bf16* Qh   = (bf16*)d_out;
    bf16* Kh   = Qh + E;
    bf16* Wcat = (bf16*)d_ws;
    bf16* VtG  = Wcat + 4 * EW;
    bf16* Yw   = VtG + E;

    const int n16w = (int)(EW / 16);         // 65536
    dim3 gw(n16w / 256, 4);                  // 256 x 4
    dim3 gqkv(M / BM, N / BN, 3);            // 64 x 8 x 3
    dim3 ga(Sc / 64, Bc * Hc);               // 32 x 64
    dim3 gg(M / BM, N / BN);                 // 64 x 8

    cvt_w4<<<gw, 256, 0, stream>>>(Wq, Wk, Wv, Wo, Wcat, n16w);
    qkv_gemm<<<gqkv, 256, 0, stream>>>(q, k, v, Wcat, bq, bk, bv,
                                       Qh, Kh, VtG, M, N, K);
    attn_flash<<<ga, 256, 0, stream>>>(Qh, Kh, VtG, Yw);
    gemm_out<<<gg, 256, 0, stream>>>(Yw, Wcat + 3 * EW, bo, out, M, N, K);
}